// Round 17
// baseline (72.985 us; speedup 1.0000x reference)
//
#include <hip/hip_runtime.h>
#include <hip/hip_bf16.h>
#include <math.h>

typedef __attribute__((ext_vector_type(4))) float f32x4;
typedef __attribute__((ext_vector_type(4))) float fvec4;
typedef __attribute__((ext_vector_type(8))) short bf16x8_t;
typedef __attribute__((ext_vector_type(4))) short bf16x4_t;

static constexpr int BATCH = 4;
static constexpr int SEQ = 4096;
static constexpr int DM = 512;
static constexpr int DA = 128;
static constexpr int BN = BATCH * SEQ;  // 16384
// split-KV: q-block = 128 rows, chunk = 384 keys (6 x 64-key tiles)
static constexpr int IPB = 187;              // sum over qb of ceil((qb+1)/3)
static constexpr int N_ITEMS = BATCH * IPB;  // 748

static constexpr float MASKV = -3.0e38f;  // finite mask (avoids inf-inf NaN)
static constexpr float MINIT = -1.0e30f;  // finite m init

static __device__ __forceinline__ unsigned short f2bf(float f) {
  unsigned u = __builtin_bit_cast(unsigned, f);
  u += 0x7fffu + ((u >> 16) & 1u);
  return (unsigned short)(u >> 16);
}
static __device__ __forceinline__ float bf2f(unsigned short u) {
  return __builtin_bit_cast(float, ((unsigned)u) << 16);
}
static __device__ __forceinline__ float fexp2(float x) {
#if __has_builtin(__builtin_amdgcn_exp2f)
  return __builtin_amdgcn_exp2f(x);
#else
  return exp2f(x);
#endif
}
static __device__ __forceinline__ unsigned pkbf(float lo, float hi) {
  unsigned r;
  asm("v_cvt_pk_bf16_f32 %0, %1, %2" : "=v"(r) : "v"(lo), "v"(hi));
  return r;
}

#define GLDS16(gsrc, ldst)                                                        \
  __builtin_amdgcn_global_load_lds(                                               \
      (const __attribute__((address_space(1))) void*)(gsrc),                      \
      (__attribute__((address_space(3))) void*)(ldst), 16, 0, 0)

// scale * log2(e): folded into Q at qkv epilogue
static constexpr float QSC = 0.08838834764831845f * 1.4426950408889634f;

// ---------------------------------------------------------------------------
// Kernel 0: weights-only prep: transpose+cast W_qkv -> [384][512],
// W_out -> [512][128].  (x cast is fused into qkv A-staging.)
// ---------------------------------------------------------------------------
__global__ __launch_bounds__(256) void prep_w_kernel(
    const float* __restrict__ Wqkv, const float* __restrict__ Wout,
    unsigned short* __restrict__ WqT, unsigned short* __restrict__ WoT) {
  int t = blockIdx.x * 256 + threadIdx.x;
  if (t < 512 * 384) {
    int k = t / 384, n = t - k * 384;
    WqT[n * 512 + k] = f2bf(Wqkv[t]);
  }
  if (t < 128 * 512) {
    int k = t >> 9, n = t & 511;
    WoT[n * 128 + k] = f2bf(Wout[t]);
  }
}

// ---------------------------------------------------------------------------
// Kernel 1: QKV projection, 128x128 tile, 8 waves, BK=64, grid (128,3).
// ROUND 17: T3-minimum 2-phase pipeline — double-buffered LDS (2x32KB),
// next tile's A-loads + B-DMA issued BEFORE compute, single drain+barrier
// AFTER compute per K-step (was: drain-before-compute + 2 barriers).
// A reg-staged from fp32 x (fused cast); B via global_load_lds.
// q: bf16 row-major [BN][128], pre-scaled by QSC.
// k: packed 32-key tiles: kpk[tile32][unit=ct*16+c*4+g][pos=token&15][8]
// v: packed 32-key tiles, sigma-permuted keys.
// [r15 lesson: keep single (128,3) grid — split kernels underfill the GPU]
// ---------------------------------------------------------------------------
__global__ __launch_bounds__(512, 4) void qkv_kernel(
    const float* __restrict__ x, const unsigned short* __restrict__ WqT,
    const float* __restrict__ bias, unsigned short* __restrict__ qbf,
    unsigned short* __restrict__ kpk, unsigned short* __restrict__ vpk) {
  __shared__ unsigned short Alds[2][128 * 64];  // 2 x 16KB, swizzled rows
  __shared__ unsigned short Blds[2][128 * 64];  // 2 x 16KB

  const int m0 = blockIdx.x * 128;
  const int n0 = blockIdx.y * 128;  // 0 / 128 / 256 -> q / k / v
  const int tid = threadIdx.x;
  const int wave = tid >> 6, lane = tid & 63;
  const int g = lane >> 4, lr = lane & 15;
  const int wm = wave >> 2, wn = wave & 3;  // wave tile: 64 rows x 32 cols

  const int srow = lane >> 3;             // row within 8-row chunk
  const int sslot = lane & 7;             // 16B slot
  const int sksw = ((sslot ^ srow) * 8);  // pre-swizzled k-offset (elements)

  f32x4 acc[4][2] = {};
  fvec4 af32[2][2];

#define LOADA(kb_)                                                             \
  do {                                                                         \
    _Pragma("unroll")                                                          \
    for (int i_ = 0; i_ < 2; ++i_) {                                           \
      int ch_ = wave * 2 + i_;                                                 \
      const float* ap_ = &x[(size_t)(m0 + ch_ * 8 + srow) * DM + (kb_) + sksw];\
      af32[i_][0] = *(const fvec4*)ap_;                                        \
      af32[i_][1] = *(const fvec4*)(ap_ + 4);                                  \
    }                                                                          \
  } while (0)
#define STAGEB(buf_, kb_)                                                      \
  do {                                                                         \
    _Pragma("unroll")                                                          \
    for (int i_ = 0; i_ < 2; ++i_) {                                           \
      int ch_ = wave * 2 + i_;                                                 \
      GLDS16(&WqT[(size_t)(n0 + ch_ * 8 + srow) * DM + (kb_) + sksw],          \
             (char*)Blds[buf_] + ch_ * 1024);                                  \
    }                                                                          \
  } while (0)
#define WRITEA(buf_)                                                           \
  do {                                                                         \
    _Pragma("unroll")                                                          \
    for (int i_ = 0; i_ < 2; ++i_) {                                           \
      int ch_ = wave * 2 + i_;                                                 \
      union { unsigned u[4]; bf16x8_t v; } pk_;                                \
      pk_.u[0] = pkbf(af32[i_][0][0], af32[i_][0][1]);                         \
      pk_.u[1] = pkbf(af32[i_][0][2], af32[i_][0][3]);                         \
      pk_.u[2] = pkbf(af32[i_][1][0], af32[i_][1][1]);                         \
      pk_.u[3] = pkbf(af32[i_][1][2], af32[i_][1][3]);                         \
      *(bf16x8_t*)&Alds[buf_][ch_ * 512 + lane * 8] = pk_.v;                   \
    }                                                                          \
  } while (0)

  // prologue: stage tile 0 into buf 0 (full drain, once)
  LOADA(0);
  STAGEB(0, 0);
  WRITEA(0);  // compiler auto-waits on af32 register deps
  asm volatile("s_waitcnt vmcnt(0) lgkmcnt(0)" ::: "memory");
  __builtin_amdgcn_s_barrier();
  __builtin_amdgcn_sched_barrier(0);

  for (int k = 0; k < 8; ++k) {
    const int cur = k & 1;
    if (k < 7) {
      LOADA((k + 1) * 64);           // 4 vmem, in flight across compute
      STAGEB(cur ^ 1, (k + 1) * 64); // 2 DMA, in flight across compute
    }

    // ---- compute tile k from buf cur ----
#pragma unroll
    for (int c2 = 0; c2 < 2; ++c2) {
      bf16x8_t ar[4], br[2];
#pragma unroll
      for (int mi = 0; mi < 4; ++mi) {
        int row = wm * 64 + mi * 16 + lr;
        ar[mi] = *(const bf16x8_t*)&Alds[cur][row * 64 + (((c2 * 4 + g) ^ (row & 7)) * 8)];
      }
#pragma unroll
      for (int ni = 0; ni < 2; ++ni) {
        int row = wn * 32 + ni * 16 + lr;
        br[ni] = *(const bf16x8_t*)&Blds[cur][row * 64 + (((c2 * 4 + g) ^ (row & 7)) * 8)];
      }
#pragma unroll
      for (int mi = 0; mi < 4; ++mi)
#pragma unroll
        for (int ni = 0; ni < 2; ++ni)
          acc[mi][ni] = __builtin_amdgcn_mfma_f32_16x16x32_bf16(ar[mi], br[ni],
                                                                acc[mi][ni], 0, 0, 0);
    }

    if (k < 7) {
      WRITEA(cur ^ 1);  // compiler waits af32; lands during MFMA tail
      asm volatile("s_waitcnt vmcnt(0) lgkmcnt(0)" ::: "memory");  // drain AFTER compute
      __builtin_amdgcn_s_barrier();
      __builtin_amdgcn_sched_barrier(0);
    }
  }
#undef LOADA
#undef STAGEB
#undef WRITEA

  if (n0 == 0) {  // Q: row-major, pre-scaled
#pragma unroll
    for (int ni = 0; ni < 2; ++ni) {
      int col = wn * 32 + ni * 16 + lr;
      float bv = bias[col];
#pragma unroll
      for (int mi = 0; mi < 4; ++mi) {
        int tokb = m0 + wm * 64 + mi * 16 + 4 * g;
#pragma unroll
        for (int r = 0; r < 4; ++r)
          qbf[(size_t)(tokb + r) * DA + col] = f2bf((acc[mi][ni][r] + bv) * QSC);
      }
    }
  } else if (n0 == 128) {  // K packed
#pragma unroll
    for (int ni = 0; ni < 2; ++ni) {
      int kd = wn * 32 + ni * 16 + lr;
      float bv = bias[128 + kd];
      int unit = (kd >> 5) * 4 + ((kd >> 3) & 3);
      int elem = kd & 7;
#pragma unroll
      for (int mi = 0; mi < 4; ++mi) {
        int tokb = m0 + wm * 64 + mi * 16 + 4 * g;
#pragma unroll
        for (int r = 0; r < 4; ++r) {
          int token = tokb + r;
          int tile32 = token >> 5;
          int u = (((token >> 4) & 1) * 16) + unit;
          kpk[(size_t)tile32 * 4096 + u * 128 + (token & 15) * 8 + elem] =
              f2bf(acc[mi][ni][r] + bv);
        }
      }
    }
  } else {  // V packed, sigma-permuted
#pragma unroll
    for (int mi = 0; mi < 4; ++mi) {
      int keyb = m0 + wm * 64 + mi * 16 + 4 * g;  // 4-aligned
      int tile32 = keyb >> 5;
      int kl0 = keyb & 31;
      int gp = (kl0 >> 2) & 3;
      int jhi = kl0 >> 4;
#pragma unroll
      for (int ni = 0; ni < 2; ++ni) {
        int d = wn * 32 + ni * 16 + lr;
        float bv = bias[256 + d];
        union { bf16x4_t v; unsigned short u[4]; } pk;
#pragma unroll
        for (int r = 0; r < 4; ++r) pk.u[r] = f2bf(acc[mi][ni][r] + bv);
        int unit = (d >> 4) * 4 + gp;
        *(bf16x4_t*)&vpk[(size_t)tile32 * 4096 + unit * 128 + (d & 15) * 8 + jhi * 4] =
            pk.v;
      }
    }
  }
}

// ---------------------------------------------------------------------------
// Online-softmax over 64 keys (s[4]) for one q-group; returns 2 packed B-frags.
// ---------------------------------------------------------------------------
static __device__ __forceinline__ void softmax64(
    f32x4 s[4], float& m_r, float& l_r, f32x4* oacc, bf16x8_t pb[2]) {
  float tmax = MASKV;
#pragma unroll
  for (int ct = 0; ct < 4; ++ct)
#pragma unroll
    for (int r = 0; r < 4; ++r) tmax = fmaxf(tmax, s[ct][r]);
  tmax = fmaxf(tmax, __shfl_xor(tmax, 16, 64));
  tmax = fmaxf(tmax, __shfl_xor(tmax, 32, 64));
  if (!__all(tmax <= m_r + 10.0f)) {  // defer-max
    float mn = fmaxf(m_r, tmax);
    float al = fexp2(m_r - mn);
    m_r = mn;
    l_r *= al;
#pragma unroll
    for (int t = 0; t < 8; ++t)
#pragma unroll
      for (int r = 0; r < 4; ++r) oacc[t][r] *= al;
  }
  float rs = 0.f;
#pragma unroll
  for (int ct = 0; ct < 4; ++ct)
#pragma unroll
    for (int r = 0; r < 4; ++r) {
      float p = fexp2(s[ct][r] - m_r);
      s[ct][r] = p;
      rs += p;
    }
  rs += __shfl_xor(rs, 16, 64);
  rs += __shfl_xor(rs, 32, 64);
  l_r += rs;
#pragma unroll
  for (int h = 0; h < 2; ++h) {
    union { unsigned u[4]; bf16x8_t v; } pk;
    pk.u[0] = pkbf(s[2 * h][0], s[2 * h][1]);
    pk.u[1] = pkbf(s[2 * h][2], s[2 * h][3]);
    pk.u[2] = pkbf(s[2 * h + 1][0], s[2 * h + 1][1]);
    pk.u[3] = pkbf(s[2 * h + 1][2], s[2 * h + 1][3]);
    pb[h] = pk.v;
  }
}

// ---------------------------------------------------------------------------
// Kernel 2: split-KV causal flash attention, swapped-QK (S^T), KVBLK=64.
// q-block = 128 rows (4 waves x 32 rows as 2 groups); chunk = 384 keys.
// LDS: K double-buffered (2x16KB) + V single-buffered (16KB) = 48KB -> 3 blk/CU.
// V staged at iter top, consumed after softmax (latency hidden under QK+softmax).
// Counted vmcnt: 8 at barrier-A (K-cur ready), 4 at barrier-C (V ready).
// [verified structure: rounds 8/10/13/14/16. Failed variants: T14 reg-staging
//  (+10us, r9), 8-wave 256-row blocks (+63us, r11), V-direct (NaN, r12)]
// ---------------------------------------------------------------------------
__global__ __launch_bounds__(256, 3) void attn_kernel(
    const unsigned short* __restrict__ qbf, const unsigned short* __restrict__ kpk,
    const unsigned short* __restrict__ vpk, const float* __restrict__ key_mask,
    unsigned short* __restrict__ part_o, float* __restrict__ part_ml,
    unsigned short* __restrict__ ctx) {
  __shared__ unsigned short Klds[2][8192];  // 16KB per buf (one 64-key tile)
  __shared__ unsigned short Vlds[8192];     // 16KB single buf

  const int flat = blockIdx.x;
  const int b = flat & 3;
  const int idxr = flat >> 2;  // 0..186, LPT: idxr 0 -> qb=31
  int rem = idxr;
  int qb = 31;
  for (;;) {
    int nc = (qb + 3) / 3;  // ceil((qb+1)/3)
    if (rem < nc) break;
    rem -= nc;
    --qb;
  }
  const int ci = rem;
  const bool direct = (qb < 3);  // single-chunk q-block
  const int key0 = ci * 384;
  const int nkeys = min(384, (qb + 1) * 128 - key0);
  const int nt = nkeys >> 6;  // 64-key tiles, 2..6

  const int tid = threadIdx.x;
  const int wave = tid >> 6, lane = tid & 63;
  const int g = lane >> 4, lr = lane & 15;
  const int q0 = wave * 16 + lr;  // group-0 row within 128-row block
  const int q1 = q0 + 64;         // group-1 row

  bf16x8_t qf0[4], qf1[4];
  {
    const unsigned short* qbase = qbf + ((size_t)(b * SEQ + qb * 128)) * DA + g * 8;
#pragma unroll
    for (int c = 0; c < 4; ++c) {
      qf0[c] = *(const bf16x8_t*)(qbase + (size_t)q0 * DA + c * 32);
      qf1[c] = *(const bf16x8_t*)(qbase + (size_t)q1 * DA + c * 32);
    }
  }

  f32x4 oacc0[8] = {}, oacc1[8] = {};
  float m0r = MINIT, l0 = 0.f, m1r = MINIT, l1 = 0.f;

  const int t32b = b * 128 + ci * 12;  // first 32-key tile of chunk
  const unsigned short* ksrc = kpk + (size_t)t32b * 4096 + wave * 2048 + lane * 8;
  const unsigned short* vsrc = vpk + (size_t)t32b * 4096 + wave * 2048 + lane * 8;

#define STAGEK(buf, tt)                                                      \
  do {                                                                       \
    char* kd_ = (char*)Klds[buf] + wave * 4096;                              \
    _Pragma("unroll")                                                        \
    for (int i_ = 0; i_ < 4; ++i_)                                           \
      GLDS16(ksrc + (size_t)(tt) * 8192 + i_ * 512, kd_ + i_ * 1024);        \
  } while (0)
#define STAGEV(tt)                                                           \
  do {                                                                       \
    char* vd_ = (char*)Vlds + wave * 4096;                                   \
    _Pragma("unroll")                                                        \
    for (int i_ = 0; i_ < 4; ++i_)                                           \
      GLDS16(vsrc + (size_t)(tt) * 8192 + i_ * 512, vd_ + i_ * 1024);        \
  } while (0)

  STAGEK(0, 0);  // prologue

  for (int tt = 0; tt < nt; ++tt) {
    const int cur = tt & 1;
    STAGEV(tt);  // V into single buf (prev reads finished at barrier-B)
    if (tt + 1 < nt) {
      STAGEK(cur ^ 1, tt + 1);
      asm volatile("s_waitcnt vmcnt(8)" ::: "memory");  // K-cur done; V+Knext fly
    } else {
      asm volatile("s_waitcnt vmcnt(4)" ::: "memory");
    }
    __builtin_amdgcn_s_barrier();  // A: K-cur visible to all waves
    __builtin_amdgcn_sched_barrier(0);

    // ---- QK^T (swapped): 64 keys, both q-groups share each K fragment ----
    f32x4 s0[4] = {}, s1[4] = {};
    __builtin_amdgcn_s_setprio(1);
#pragma unroll
    for (int ct = 0; ct < 4; ++ct)
#pragma unroll
      for (int c = 0; c < 4; ++c) {
        bf16x8_t kf = *(const bf16x8_t*)&Klds[cur][(ct >> 1) * 4096 +
                                                   (((ct & 1) * 16 + c * 4 + g) * 16 + lr) * 8];
        s0[ct] = __builtin_amdgcn_mfma_f32_16x16x32_bf16(kf, qf0[c], s0[ct], 0, 0, 0);
        s1[ct] = __builtin_amdgcn_mfma_f32_16x16x32_bf16(kf, qf1[c], s1[ct], 0, 0, 0);
      }
    __builtin_amdgcn_s_setprio(0);

    // ---- causal mask (finite mask value) ----
    const int koff = key0 + tt * 64 - qb * 128;
    if (koff + 63 > wave * 16) {
      int thr = q0 - koff;
#pragma unroll
      for (int ct = 0; ct < 4; ++ct)
#pragma unroll
        for (int r = 0; r < 4; ++r)
          if (16 * ct + 4 * g + r > thr) s0[ct][r] = MASKV;
    }
    if (koff + 63 > 64 + wave * 16) {
      int thr = q1 - koff;
#pragma unroll
      for (int ct = 0; ct < 4; ++ct)
#pragma unroll
        for (int r = 0; r < 4; ++r)
          if (16 * ct + 4 * g + r > thr) s1[ct][r] = MASKV;
    }

    // ---- online softmax per group (V staging lands during this) ----
    bf16x8_t pb0[2], pb1[2];
    softmax64(s0, m0r, l0, oacc0, pb0);
    softmax64(s1, m1r, l1, oacc1, pb1);

    if (tt + 1 < nt) {
      asm volatile("s_waitcnt vmcnt(4)" ::: "memory");  // V done; Knext flies
    } else {
      asm volatile("s_waitcnt vmcnt(0)" ::: "memory");
    }
    __builtin_amdgcn_s_barrier();  // C: V visible to all waves
    __builtin_amdgcn_sched_barrier(0);

    // ---- PV: both groups share each V fragment ----
    __builtin_amdgcn_s_setprio(1);
#pragma unroll
    for (int t = 0; t < 8; ++t)
#pragma unroll
      for (int h = 0; h < 2; ++h) {
        bf16x8_t vf = *(const bf16x8_t*)&Vlds[h * 4096 + ((t * 4 + g) * 16 + lr) * 8];
        oacc0[t] = __builtin_amdgcn_mfma_f32_16x16x32_bf16(vf, pb0[h], oacc0[t], 0, 0, 0);
        oacc1[t] = __builtin_amdgcn_mfma_f32_16x16x32_bf16(vf, pb1[h], oacc1[t], 0, 0, 0);
      }
    __builtin_amdgcn_s_setprio(0);

    __builtin_amdgcn_s_barrier();  // B: K[cur]/V reads done -> next STAGE safe
  }
#undef STAGEK
#undef STAGEV

  // ---- epilogue: lane owns q-rows q0 and q1; d = 16t + 4g + r ----
  const int slot = b * IPB + idxr;
#pragma unroll
  for (int grp = 0; grp < 2; ++grp) {
    const int row = grp ? q1 : q0;
    const f32x4* oa = grp ? oacc1 : oacc0;
    const float mr = grp ? m1r : m0r;
    const float lr_ = grp ? l1 : l0;
    if (direct) {
      float km = key_mask[b * SEQ + qb * 128 + row];
      float inv = km / lr_;
      unsigned short* co = ctx + ((size_t)(b * SEQ + qb * 128 + row)) * DA;
#pragma unroll
      for (int t = 0; t < 8; ++t) {
        union { bf16x4_t v; unsigned short u[4]; } pk;
#pragma unroll
        for (int r = 0; r < 4; ++r) pk.u[r] = f2bf(oa[t][r] * inv);
        *(bf16x4_t*)&co[t * 16 + 4 * g] = pk.v;
      }
    } else {
      unsigned short* po = part_o + (size_t)slot * 16384 + (size_t)row * 128;
#pragma unroll
      for (int t = 0; t < 8; ++t) {
        union { bf16x4_t v; unsigned short u[4]; } pk;
#pragma unroll
        for (int r = 0; r < 4; ++r) pk.u[r] = f2bf(oa[t][r]);
        *(bf16x4_t*)&po[t * 16 + 4 * g] = pk.v;
      }
      if (g == 0) {
        float2 ml = make_float2(mr, lr_);
        *(float2*)&part_ml[((size_t)slot * 128 + row) * 2] = ml;
      }
    }
  }
}

// ---------------------------------------------------------------------------
// Kernel 2b: combine partials -> ctx for qb >= 3.
// grid (29*4, 4): block = 32 rows of one q-block; 512 threads = 32 rows x 16
// col-groups of 8.
// ---------------------------------------------------------------------------
__global__ __launch_bounds__(512) void combine_kernel(
    const unsigned short* __restrict__ part_o, const float* __restrict__ part_ml,
    const float* __restrict__ key_mask, unsigned short* __restrict__ ctx) {
  const int qb = 3 + (blockIdx.x >> 2);
  const int rq = blockIdx.x & 3;
  const int b = blockIdx.y;
  const int nc = (qb + 3) / 3;
  int idx0 = 0;
  for (int q = 31; q > qb; --q) idx0 += (q + 3) / 3;
  const int row = rq * 32 + (threadIdx.x >> 4);  // row within 128-row q-block
  const int cs = threadIdx.x & 15;               // 8-col group

  float m = MINIT;
  for (int ci = 0; ci < nc; ++ci) {
    int slot = b * IPB + idx0 + ci;
    m = fmaxf(m, part_ml[((size_t)slot * 128 + row) * 2 + 0]);
  }
  float l = 0.f;
  float acc[8];
#pragma unroll
  for (int k = 0; k < 8; ++k) acc[k] = 0.f;
  for (int ci = 0; ci < nc; ++ci) {
    int slot = b * IPB + idx0 + ci;
    float mi = part_ml[((size_t)slot * 128 + row) * 2 + 0];
    float li = part_ml[((size_t)slot * 128 + row) * 2 + 1];
    float w = fexp2(mi - m);
    l += w * li;
    const unsigned short* po =
        part_o + (size_t)slot * 16384 + (size_t)row * 128 + cs * 8;
    bf16x8_t v = *(const bf16x8_t*)po;
#pragma unroll
    for (int jj = 0; jj < 8; ++jj) acc[jj] += w * bf2f((unsigned short)v[jj]);
  }
  int rowg = b * SEQ + qb * 128 + row;
  float sc = key_mask[rowg] / l;
  union { bf16x8_t v; unsigned short u[8]; } pk;
#pragma unroll
  for (int jj = 0; jj < 8; ++jj) pk.u[jj] = f2bf(acc[jj] * sc);
  *(bf16x8_t*)&ctx[(size_t)rowg * 128 + cs * 8] = pk.v;
}

// ---------------------------------------------------------------------------
// Kernel 3: output projection, 128x128 tile, 8 waves, BK=64 (qkv skeleton).
// [16384,128] @ [128,512] + bias -> fp32 out.  grid (128, 4).
// ---------------------------------------------------------------------------
__global__ __launch_bounds__(512, 4) void outproj_kernel(
    const unsigned short* __restrict__ ctx, const unsigned short* __restrict__ WoT,
    const float* __restrict__ bias, float* __restrict__ out) {
  __shared__ unsigned short Alds[128 * 64];
  __shared__ unsigned short Blds[128 * 64];

  const int m0 = blockIdx.x * 128;
  const int n0 = blockIdx.y * 128;
  const int tid = threadIdx.x;
  const int wave = tid >> 6, lane = tid & 63;
  const int g = lane >> 4, lr = lane & 15;
  const int wm = wave >> 2, wn = wave & 3;  // wave tile: 64 rows x 32 cols

  const int srow = lane >> 3;
  const int sslot = lane & 7;
  const int sksw = ((sslot ^ srow) * 8);

  f32x4 acc[4][2] = {};

  for (int kb = 0; kb < DA; kb += 64) {
    __syncthreads();
#pragma unroll
    for (int i = 0; i < 2; ++i) {
      int ch = wave * 2 + i;
      GLDS16(&ctx[(size_t)(m0 + ch * 8 + srow) * DA + kb + sksw],
             (char*)Alds + ch * 1024);
      GLDS16(&WoT[(size_t)(n0 + ch * 8 + srow) * DA + kb + sksw],
             (char*)Blds + ch * 1024);
    }
    asm volatile("s_waitcnt vmcnt(0)" ::: "memory");
    __syncthreads();

#pragma unroll
    for (int c2 = 0; c2 < 2; ++c2) {
      bf16x8_t ar[4], br[2];
#pragma unroll
      for (int mi = 0; mi < 4; ++mi) {
        int row = wm * 64 + mi * 16 + lr;
        ar[mi] = *(const bf16x8_t*)&Alds[row * 64 + (((c2 * 4 + g) ^ (row & 7)) * 8)];
      }
#pragma unroll
      for (int ni = 0; ni < 2; ++ni) {
        int row = wn * 32 + ni * 16 + lr;
        br[ni] = *(const bf16x8_t*)&Blds[row * 64 + (((c2 * 4 + g) ^ (row & 7)) * 8)];
      }
#pragma unroll
      for (int mi = 0; mi < 4; ++mi)
#pragma unroll
        for (int ni = 0; ni < 2; ++ni)
          acc[mi][ni] = __builtin_amdgcn_mfma_f32_16x16x32_bf16(ar[mi], br[ni],
                                                                acc[mi][ni], 0, 0, 0);
    }
  }

#pragma unroll
  for (int ni = 0; ni < 2; ++ni) {
    int col = n0 + wn * 32 + ni * 16 + lr;
    float bv = bias[col];
#pragma unroll
    for (int mi = 0; mi < 4; ++mi) {
      int tokb = m0 + wm * 64 + mi * 16 + 4 * g;
#pragma unroll
      for (int r = 0; r < 4; ++r)
        out[(size_t)(tokb + r) * DM + col] = acc[mi][ni][r] + bv;
    }
  }
}

// ---------------------------------------------------------------------------
extern "C" void kernel_launch(void* const* d_in, const int* in_sizes, int n_in,
                              void* d_out, int out_size, void* d_ws, size_t ws_size,
                              hipStream_t stream) {
  const float* x = (const float*)d_in[0];
  const float* key_mask = (const float*)d_in[1];
  const float* W_qkv = (const float*)d_in[2];
  const float* b_qkv = (const float*)d_in[3];
  const float* W_out = (const float*)d_in[4];
  const float* b_out = (const float*)d_in[5];
  float* out = (float*)d_out;

  unsigned short* ws = (unsigned short*)d_ws;
  unsigned short* qbf = ws;                        // [BN][128] bf16 (pre-scaled)
  unsigned short* kpk = qbf + (size_t)BN * DA;     // packed K 32-tiles
  unsigned short* vpk = kpk + (size_t)BN * DA;     // packed V 32-tiles (sigma)
  unsigned short* ctx = vpk + (size_t)BN * DA;     // [BN][128] bf16
  unsigned short* xbf = ctx + (size_t)BN * DA;     // (unused region, kept for layout)
  unsigned short* WqT = xbf + (size_t)BN * DM;     // [384][512]
  unsigned short* WoT = WqT + (size_t)384 * 512;   // [512][128]
  // partials in their own region (ws is 256 MiB; ~60 MB used total)
  unsigned short* part_o = WoT + (size_t)512 * 128;         // [748][128][128] bf16
  float* part_ml = (float*)(part_o + (size_t)N_ITEMS * 16384);  // [748][128][2] f32

  prep_w_kernel<<<dim3(768), 256, 0, stream>>>(W_qkv, W_out, WqT, WoT);
  qkv_kernel<<<dim3(BN / 128, 3), 512, 0, stream>>>(x, WqT, b_qkv, qbf, kpk, vpk);
  attn_kernel<<<dim3(N_ITEMS), 256, 0, stream>>>(qbf, kpk, vpk, key_mask,
                                                 part_o, part_ml, ctx);
  combine_kernel<<<dim3(29 * 4, 4), 512, 0, stream>>>(part_o, part_ml, key_mask, ctx);
  outproj_kernel<<<dim3(BN / 128, 4), 512, 0, stream>>>(ctx, WoT, b_out, out);
}

// Round 18
// 72.765 us; speedup vs baseline: 1.0030x; 1.0030x over previous
//
#include <hip/hip_runtime.h>
#include <hip/hip_bf16.h>
#include <math.h>

typedef __attribute__((ext_vector_type(4))) float f32x4;
typedef __attribute__((ext_vector_type(4))) float fvec4;
typedef __attribute__((ext_vector_type(8))) short bf16x8_t;
typedef __attribute__((ext_vector_type(4))) short bf16x4_t;

static constexpr int BATCH = 4;
static constexpr int SEQ = 4096;
static constexpr int DM = 512;
static constexpr int DA = 128;
static constexpr int BN = BATCH * SEQ;  // 16384
// split-KV: q-block = 128 rows, chunk = 384 keys (6 x 64-key tiles)
static constexpr int IPB = 187;              // sum over qb of ceil((qb+1)/3)
static constexpr int N_ITEMS = BATCH * IPB;  // 748

static constexpr float MASKV = -3.0e38f;  // finite mask (avoids inf-inf NaN)
static constexpr float MINIT = -1.0e30f;  // finite m init

static __device__ __forceinline__ unsigned short f2bf(float f) {
  unsigned u = __builtin_bit_cast(unsigned, f);
  u += 0x7fffu + ((u >> 16) & 1u);
  return (unsigned short)(u >> 16);
}
static __device__ __forceinline__ float bf2f(unsigned short u) {
  return __builtin_bit_cast(float, ((unsigned)u) << 16);
}
static __device__ __forceinline__ float fexp2(float x) {
#if __has_builtin(__builtin_amdgcn_exp2f)
  return __builtin_amdgcn_exp2f(x);
#else
  return exp2f(x);
#endif
}
static __device__ __forceinline__ unsigned pkbf(float lo, float hi) {
  unsigned r;
  asm("v_cvt_pk_bf16_f32 %0, %1, %2" : "=v"(r) : "v"(lo), "v"(hi));
  return r;
}

#define GLDS16(gsrc, ldst)                                                        \
  __builtin_amdgcn_global_load_lds(                                               \
      (const __attribute__((address_space(1))) void*)(gsrc),                      \
      (__attribute__((address_space(3))) void*)(ldst), 16, 0, 0)

// scale * log2(e): folded into Q at qkv epilogue
static constexpr float QSC = 0.08838834764831845f * 1.4426950408889634f;

// ---------------------------------------------------------------------------
// Kernel 0: weights-only prep: transpose+cast W_qkv -> [384][512],
// W_out -> [512][128].  (x cast is fused into qkv A-staging.)
// ---------------------------------------------------------------------------
__global__ __launch_bounds__(256) void prep_w_kernel(
    const float* __restrict__ Wqkv, const float* __restrict__ Wout,
    unsigned short* __restrict__ WqT, unsigned short* __restrict__ WoT) {
  int t = blockIdx.x * 256 + threadIdx.x;
  if (t < 512 * 384) {
    int k = t / 384, n = t - k * 384;
    WqT[n * 512 + k] = f2bf(Wqkv[t]);
  }
  if (t < 128 * 512) {
    int k = t >> 9, n = t & 511;
    WoT[n * 128 + k] = f2bf(Wout[t]);
  }
}

// ---------------------------------------------------------------------------
// Kernel 1: QKV projection, 128x128 tile, 8 waves, BK=64, grid (128,3).
// B staged via global_load_lds (pre-swizzled source).
// A staged REG-PATH directly from fp32 x with fused cast (cvt_pk RNE).
// [r15: splitting into 128-block kernels underfills the GPU (+14us).
//  r17: 2-phase dbuf pipeline NEUTRAL — TLP already hides staging latency]
// q: bf16 row-major [BN][128], pre-scaled by QSC.
// k: packed 32-key tiles: kpk[tile32][unit=ct*16+c*4+g][pos=token&15][8]
// v: packed 32-key tiles, sigma-permuted keys.
// ---------------------------------------------------------------------------
__global__ __launch_bounds__(512, 4) void qkv_kernel(
    const float* __restrict__ x, const unsigned short* __restrict__ WqT,
    const float* __restrict__ bias, unsigned short* __restrict__ qbf,
    unsigned short* __restrict__ kpk, unsigned short* __restrict__ vpk) {
  __shared__ unsigned short Alds[128 * 64];  // rows of 64 shorts (128B), swizzled
  __shared__ unsigned short Blds[128 * 64];

  const int m0 = blockIdx.x * 128;
  const int n0 = blockIdx.y * 128;  // 0 / 128 / 256 -> q / k / v
  const int tid = threadIdx.x;
  const int wave = tid >> 6, lane = tid & 63;
  const int g = lane >> 4, lr = lane & 15;
  const int wm = wave >> 2, wn = wave & 3;  // wave tile: 64 rows x 32 cols

  const int srow = lane >> 3;             // row within 8-row chunk
  const int sslot = lane & 7;             // 16B slot
  const int sksw = ((sslot ^ srow) * 8);  // pre-swizzled k-offset (elements)

  f32x4 acc[4][2] = {};

  for (int kb = 0; kb < DM; kb += 64) {
    __syncthreads();  // readers done with LDS
    // B: async DMA from pre-transposed bf16 weights
#pragma unroll
    for (int i = 0; i < 2; ++i) {
      int ch = wave * 2 + i;  // chunk id 0..15, covers rows 8ch..8ch+7
      GLDS16(&WqT[(size_t)(n0 + ch * 8 + srow) * DM + kb + sksw],
             (char*)Blds + ch * 1024);
    }
    // A: fp32 loads (issue early)
    fvec4 af32[2][2];
#pragma unroll
    for (int i = 0; i < 2; ++i) {
      int ch = wave * 2 + i;
      const float* ap = &x[(size_t)(m0 + ch * 8 + srow) * DM + kb + sksw];
      af32[i][0] = *(const fvec4*)ap;
      af32[i][1] = *(const fvec4*)(ap + 4);
    }
    // A: convert + LDS write (same linear dest the DMA used)
#pragma unroll
    for (int i = 0; i < 2; ++i) {
      int ch = wave * 2 + i;
      union { unsigned u[4]; bf16x8_t v; } pk;
      pk.u[0] = pkbf(af32[i][0][0], af32[i][0][1]);
      pk.u[1] = pkbf(af32[i][0][2], af32[i][0][3]);
      pk.u[2] = pkbf(af32[i][1][0], af32[i][1][1]);
      pk.u[3] = pkbf(af32[i][1][2], af32[i][1][3]);
      *(bf16x8_t*)&Alds[ch * 512 + lane * 8] = pk.v;
    }
    asm volatile("s_waitcnt vmcnt(0)" ::: "memory");  // B DMA done
    __syncthreads();                                  // (barrier drains lgkm)

#pragma unroll
    for (int c2 = 0; c2 < 2; ++c2) {
      bf16x8_t ar[4], br[2];
#pragma unroll
      for (int mi = 0; mi < 4; ++mi) {
        int row = wm * 64 + mi * 16 + lr;
        ar[mi] = *(const bf16x8_t*)&Alds[row * 64 + (((c2 * 4 + g) ^ (row & 7)) * 8)];
      }
#pragma unroll
      for (int ni = 0; ni < 2; ++ni) {
        int row = wn * 32 + ni * 16 + lr;
        br[ni] = *(const bf16x8_t*)&Blds[row * 64 + (((c2 * 4 + g) ^ (row & 7)) * 8)];
      }
#pragma unroll
      for (int mi = 0; mi < 4; ++mi)
#pragma unroll
        for (int ni = 0; ni < 2; ++ni)
          acc[mi][ni] = __builtin_amdgcn_mfma_f32_16x16x32_bf16(ar[mi], br[ni],
                                                                acc[mi][ni], 0, 0, 0);
    }
  }

  if (n0 == 0) {  // Q: row-major, pre-scaled
#pragma unroll
    for (int ni = 0; ni < 2; ++ni) {
      int col = wn * 32 + ni * 16 + lr;
      float bv = bias[col];
#pragma unroll
      for (int mi = 0; mi < 4; ++mi) {
        int tokb = m0 + wm * 64 + mi * 16 + 4 * g;
#pragma unroll
        for (int r = 0; r < 4; ++r)
          qbf[(size_t)(tokb + r) * DA + col] = f2bf((acc[mi][ni][r] + bv) * QSC);
      }
    }
  } else if (n0 == 128) {  // K packed
#pragma unroll
    for (int ni = 0; ni < 2; ++ni) {
      int kd = wn * 32 + ni * 16 + lr;
      float bv = bias[128 + kd];
      int unit = (kd >> 5) * 4 + ((kd >> 3) & 3);
      int elem = kd & 7;
#pragma unroll
      for (int mi = 0; mi < 4; ++mi) {
        int tokb = m0 + wm * 64 + mi * 16 + 4 * g;
#pragma unroll
        for (int r = 0; r < 4; ++r) {
          int token = tokb + r;
          int tile32 = token >> 5;
          int u = (((token >> 4) & 1) * 16) + unit;
          kpk[(size_t)tile32 * 4096 + u * 128 + (token & 15) * 8 + elem] =
              f2bf(acc[mi][ni][r] + bv);
        }
      }
    }
  } else {  // V packed, sigma-permuted
#pragma unroll
    for (int mi = 0; mi < 4; ++mi) {
      int keyb = m0 + wm * 64 + mi * 16 + 4 * g;  // 4-aligned
      int tile32 = keyb >> 5;
      int kl0 = keyb & 31;
      int gp = (kl0 >> 2) & 3;
      int jhi = kl0 >> 4;
#pragma unroll
      for (int ni = 0; ni < 2; ++ni) {
        int d = wn * 32 + ni * 16 + lr;
        float bv = bias[256 + d];
        union { bf16x4_t v; unsigned short u[4]; } pk;
#pragma unroll
        for (int r = 0; r < 4; ++r) pk.u[r] = f2bf(acc[mi][ni][r] + bv);
        int unit = (d >> 4) * 4 + gp;
        *(bf16x4_t*)&vpk[(size_t)tile32 * 4096 + unit * 128 + (d & 15) * 8 + jhi * 4] =
            pk.v;
      }
    }
  }
}

// ---------------------------------------------------------------------------
// Online-softmax over 64 keys (s[4]) for one q-group; returns 2 packed B-frags.
// ---------------------------------------------------------------------------
static __device__ __forceinline__ void softmax64(
    f32x4 s[4], float& m_r, float& l_r, f32x4* oacc, bf16x8_t pb[2]) {
  float tmax = MASKV;
#pragma unroll
  for (int ct = 0; ct < 4; ++ct)
#pragma unroll
    for (int r = 0; r < 4; ++r) tmax = fmaxf(tmax, s[ct][r]);
  tmax = fmaxf(tmax, __shfl_xor(tmax, 16, 64));
  tmax = fmaxf(tmax, __shfl_xor(tmax, 32, 64));
  if (!__all(tmax <= m_r + 10.0f)) {  // defer-max
    float mn = fmaxf(m_r, tmax);
    float al = fexp2(m_r - mn);
    m_r = mn;
    l_r *= al;
#pragma unroll
    for (int t = 0; t < 8; ++t)
#pragma unroll
      for (int r = 0; r < 4; ++r) oacc[t][r] *= al;
  }
  float rs = 0.f;
#pragma unroll
  for (int ct = 0; ct < 4; ++ct)
#pragma unroll
    for (int r = 0; r < 4; ++r) {
      float p = fexp2(s[ct][r] - m_r);
      s[ct][r] = p;
      rs += p;
    }
  rs += __shfl_xor(rs, 16, 64);
  rs += __shfl_xor(rs, 32, 64);
  l_r += rs;
#pragma unroll
  for (int h = 0; h < 2; ++h) {
    union { unsigned u[4]; bf16x8_t v; } pk;
    pk.u[0] = pkbf(s[2 * h][0], s[2 * h][1]);
    pk.u[1] = pkbf(s[2 * h][2], s[2 * h][3]);
    pk.u[2] = pkbf(s[2 * h + 1][0], s[2 * h + 1][1]);
    pk.u[3] = pkbf(s[2 * h + 1][2], s[2 * h + 1][3]);
    pb[h] = pk.v;
  }
}

// ---------------------------------------------------------------------------
// Kernel 2: split-KV causal flash attention, swapped-QK (S^T), KVBLK=64.
// q-block = 128 rows (4 waves x 32 rows as 2 groups); chunk = 384 keys.
// LDS: K double-buffered (2x16KB) + V single-buffered (16KB) = 48KB -> 3 blk/CU.
// V staged at iter top, consumed after softmax (latency hidden under QK+softmax).
// Counted vmcnt: 8 at barrier-A (K-cur ready), 4 at barrier-C (V ready).
// [verified structure: rounds 8/10/13/14/16. Failed variants: T14 reg-staging
//  (+10us, r9), 8-wave 256-row blocks (+63us, r11), V-direct (NaN, r12)]
// ---------------------------------------------------------------------------
__global__ __launch_bounds__(256, 3) void attn_kernel(
    const unsigned short* __restrict__ qbf, const unsigned short* __restrict__ kpk,
    const unsigned short* __restrict__ vpk, const float* __restrict__ key_mask,
    unsigned short* __restrict__ part_o, float* __restrict__ part_ml,
    unsigned short* __restrict__ ctx) {
  __shared__ unsigned short Klds[2][8192];  // 16KB per buf (one 64-key tile)
  __shared__ unsigned short Vlds[8192];     // 16KB single buf

  const int flat = blockIdx.x;
  const int b = flat & 3;
  const int idxr = flat >> 2;  // 0..186, LPT: idxr 0 -> qb=31
  int rem = idxr;
  int qb = 31;
  for (;;) {
    int nc = (qb + 3) / 3;  // ceil((qb+1)/3)
    if (rem < nc) break;
    rem -= nc;
    --qb;
  }
  const int ci = rem;
  const bool direct = (qb < 3);  // single-chunk q-block
  const int key0 = ci * 384;
  const int nkeys = min(384, (qb + 1) * 128 - key0);
  const int nt = nkeys >> 6;  // 64-key tiles, 2..6

  const int tid = threadIdx.x;
  const int wave = tid >> 6, lane = tid & 63;
  const int g = lane >> 4, lr = lane & 15;
  const int q0 = wave * 16 + lr;  // group-0 row within 128-row block
  const int q1 = q0 + 64;         // group-1 row

  bf16x8_t qf0[4], qf1[4];
  {
    const unsigned short* qbase = qbf + ((size_t)(b * SEQ + qb * 128)) * DA + g * 8;
#pragma unroll
    for (int c = 0; c < 4; ++c) {
      qf0[c] = *(const bf16x8_t*)(qbase + (size_t)q0 * DA + c * 32);
      qf1[c] = *(const bf16x8_t*)(qbase + (size_t)q1 * DA + c * 32);
    }
  }

  f32x4 oacc0[8] = {}, oacc1[8] = {};
  float m0r = MINIT, l0 = 0.f, m1r = MINIT, l1 = 0.f;

  const int t32b = b * 128 + ci * 12;  // first 32-key tile of chunk
  const unsigned short* ksrc = kpk + (size_t)t32b * 4096 + wave * 2048 + lane * 8;
  const unsigned short* vsrc = vpk + (size_t)t32b * 4096 + wave * 2048 + lane * 8;

#define STAGEK(buf, tt)                                                      \
  do {                                                                       \
    char* kd_ = (char*)Klds[buf] + wave * 4096;                              \
    _Pragma("unroll")                                                        \
    for (int i_ = 0; i_ < 4; ++i_)                                           \
      GLDS16(ksrc + (size_t)(tt) * 8192 + i_ * 512, kd_ + i_ * 1024);        \
  } while (0)
#define STAGEV(tt)                                                           \
  do {                                                                       \
    char* vd_ = (char*)Vlds + wave * 4096;                                   \
    _Pragma("unroll")                                                        \
    for (int i_ = 0; i_ < 4; ++i_)                                           \
      GLDS16(vsrc + (size_t)(tt) * 8192 + i_ * 512, vd_ + i_ * 1024);        \
  } while (0)

  STAGEK(0, 0);  // prologue

  for (int tt = 0; tt < nt; ++tt) {
    const int cur = tt & 1;
    STAGEV(tt);  // V into single buf (prev reads finished at barrier-B)
    if (tt + 1 < nt) {
      STAGEK(cur ^ 1, tt + 1);
      asm volatile("s_waitcnt vmcnt(8)" ::: "memory");  // K-cur done; V+Knext fly
    } else {
      asm volatile("s_waitcnt vmcnt(4)" ::: "memory");
    }
    __builtin_amdgcn_s_barrier();  // A: K-cur visible to all waves
    __builtin_amdgcn_sched_barrier(0);

    // ---- QK^T (swapped): 64 keys, both q-groups share each K fragment ----
    f32x4 s0[4] = {}, s1[4] = {};
    __builtin_amdgcn_s_setprio(1);
#pragma unroll
    for (int ct = 0; ct < 4; ++ct)
#pragma unroll
      for (int c = 0; c < 4; ++c) {
        bf16x8_t kf = *(const bf16x8_t*)&Klds[cur][(ct >> 1) * 4096 +
                                                   (((ct & 1) * 16 + c * 4 + g) * 16 + lr) * 8];
        s0[ct] = __builtin_amdgcn_mfma_f32_16x16x32_bf16(kf, qf0[c], s0[ct], 0, 0, 0);
        s1[ct] = __builtin_amdgcn_mfma_f32_16x16x32_bf16(kf, qf1[c], s1[ct], 0, 0, 0);
      }
    __builtin_amdgcn_s_setprio(0);

    // ---- causal mask (finite mask value) ----
    const int koff = key0 + tt * 64 - qb * 128;
    if (koff + 63 > wave * 16) {
      int thr = q0 - koff;
#pragma unroll
      for (int ct = 0; ct < 4; ++ct)
#pragma unroll
        for (int r = 0; r < 4; ++r)
          if (16 * ct + 4 * g + r > thr) s0[ct][r] = MASKV;
    }
    if (koff + 63 > 64 + wave * 16) {
      int thr = q1 - koff;
#pragma unroll
      for (int ct = 0; ct < 4; ++ct)
#pragma unroll
        for (int r = 0; r < 4; ++r)
          if (16 * ct + 4 * g + r > thr) s1[ct][r] = MASKV;
    }

    // ---- online softmax per group (V staging lands during this) ----
    bf16x8_t pb0[2], pb1[2];
    softmax64(s0, m0r, l0, oacc0, pb0);
    softmax64(s1, m1r, l1, oacc1, pb1);

    if (tt + 1 < nt) {
      asm volatile("s_waitcnt vmcnt(4)" ::: "memory");  // V done; Knext flies
    } else {
      asm volatile("s_waitcnt vmcnt(0)" ::: "memory");
    }
    __builtin_amdgcn_s_barrier();  // C: V visible to all waves
    __builtin_amdgcn_sched_barrier(0);

    // ---- PV: both groups share each V fragment ----
    __builtin_amdgcn_s_setprio(1);
#pragma unroll
    for (int t = 0; t < 8; ++t)
#pragma unroll
      for (int h = 0; h < 2; ++h) {
        bf16x8_t vf = *(const bf16x8_t*)&Vlds[h * 4096 + ((t * 4 + g) * 16 + lr) * 8];
        oacc0[t] = __builtin_amdgcn_mfma_f32_16x16x32_bf16(vf, pb0[h], oacc0[t], 0, 0, 0);
        oacc1[t] = __builtin_amdgcn_mfma_f32_16x16x32_bf16(vf, pb1[h], oacc1[t], 0, 0, 0);
      }
    __builtin_amdgcn_s_setprio(0);

    __builtin_amdgcn_s_barrier();  // B: K[cur]/V reads done -> next STAGE safe
  }
#undef STAGEK
#undef STAGEV

  // ---- epilogue: lane owns q-rows q0 and q1; d = 16t + 4g + r ----
  const int slot = b * IPB + idxr;
#pragma unroll
  for (int grp = 0; grp < 2; ++grp) {
    const int row = grp ? q1 : q0;
    const f32x4* oa = grp ? oacc1 : oacc0;
    const float mr = grp ? m1r : m0r;
    const float lr_ = grp ? l1 : l0;
    if (direct) {
      float km = key_mask[b * SEQ + qb * 128 + row];
      float inv = km / lr_;
      unsigned short* co = ctx + ((size_t)(b * SEQ + qb * 128 + row)) * DA;
#pragma unroll
      for (int t = 0; t < 8; ++t) {
        union { bf16x4_t v; unsigned short u[4]; } pk;
#pragma unroll
        for (int r = 0; r < 4; ++r) pk.u[r] = f2bf(oa[t][r] * inv);
        *(bf16x4_t*)&co[t * 16 + 4 * g] = pk.v;
      }
    } else {
      unsigned short* po = part_o + (size_t)slot * 16384 + (size_t)row * 128;
#pragma unroll
      for (int t = 0; t < 8; ++t) {
        union { bf16x4_t v; unsigned short u[4]; } pk;
#pragma unroll
        for (int r = 0; r < 4; ++r) pk.u[r] = f2bf(oa[t][r]);
        *(bf16x4_t*)&po[t * 16 + 4 * g] = pk.v;
      }
      if (g == 0) {
        float2 ml = make_float2(mr, lr_);
        *(float2*)&part_ml[((size_t)slot * 128 + row) * 2] = ml;
      }
    }
  }
}

// ---------------------------------------------------------------------------
// Kernel 2b: combine partials -> ctx for qb >= 3.
// grid (29*4, 4): block = 32 rows of one q-block; 512 threads = 32 rows x 16
// col-groups of 8.
// ---------------------------------------------------------------------------
__global__ __launch_bounds__(512) void combine_kernel(
    const unsigned short* __restrict__ part_o, const float* __restrict__ part_ml,
    const float* __restrict__ key_mask, unsigned short* __restrict__ ctx) {
  const int qb = 3 + (blockIdx.x >> 2);
  const int rq = blockIdx.x & 3;
  const int b = blockIdx.y;
  const int nc = (qb + 3) / 3;
  int idx0 = 0;
  for (int q = 31; q > qb; --q) idx0 += (q + 3) / 3;
  const int row = rq * 32 + (threadIdx.x >> 4);  // row within 128-row q-block
  const int cs = threadIdx.x & 15;               // 8-col group

  float m = MINIT;
  for (int ci = 0; ci < nc; ++ci) {
    int slot = b * IPB + idx0 + ci;
    m = fmaxf(m, part_ml[((size_t)slot * 128 + row) * 2 + 0]);
  }
  float l = 0.f;
  float acc[8];
#pragma unroll
  for (int k = 0; k < 8; ++k) acc[k] = 0.f;
  for (int ci = 0; ci < nc; ++ci) {
    int slot = b * IPB + idx0 + ci;
    float mi = part_ml[((size_t)slot * 128 + row) * 2 + 0];
    float li = part_ml[((size_t)slot * 128 + row) * 2 + 1];
    float w = fexp2(mi - m);
    l += w * li;
    const unsigned short* po =
        part_o + (size_t)slot * 16384 + (size_t)row * 128 + cs * 8;
    bf16x8_t v = *(const bf16x8_t*)po;
#pragma unroll
    for (int jj = 0; jj < 8; ++jj) acc[jj] += w * bf2f((unsigned short)v[jj]);
  }
  int rowg = b * SEQ + qb * 128 + row;
  float sc = key_mask[rowg] / l;
  union { bf16x8_t v; unsigned short u[8]; } pk;
#pragma unroll
  for (int jj = 0; jj < 8; ++jj) pk.u[jj] = f2bf(acc[jj] * sc);
  *(bf16x8_t*)&ctx[(size_t)rowg * 128 + cs * 8] = pk.v;
}

// ---------------------------------------------------------------------------
// Kernel 3: output projection, 128x128 tile, 8 waves, BK=64 (qkv skeleton).
// [16384,128] @ [128,512] + bias -> fp32 out.  grid (128, 4).
// ---------------------------------------------------------------------------
__global__ __launch_bounds__(512, 4) void outproj_kernel(
    const unsigned short* __restrict__ ctx, const unsigned short* __restrict__ WoT,
    const float* __restrict__ bias, float* __restrict__ out) {
  __shared__ unsigned short Alds[128 * 64];
  __shared__ unsigned short Blds[128 * 64];

  const int m0 = blockIdx.x * 128;
  const int n0 = blockIdx.y * 128;
  const int tid = threadIdx.x;
  const int wave = tid >> 6, lane = tid & 63;
  const int g = lane >> 4, lr = lane & 15;
  const int wm = wave >> 2, wn = wave & 3;  // wave tile: 64 rows x 32 cols

  const int srow = lane >> 3;
  const int sslot = lane & 7;
  const int sksw = ((sslot ^ srow) * 8);

  f32x4 acc[4][2] = {};

  for (int kb = 0; kb < DA; kb += 64) {
    __syncthreads();
#pragma unroll
    for (int i = 0; i < 2; ++i) {
      int ch = wave * 2 + i;
      GLDS16(&ctx[(size_t)(m0 + ch * 8 + srow) * DA + kb + sksw],
             (char*)Alds + ch * 1024);
      GLDS16(&WoT[(size_t)(n0 + ch * 8 + srow) * DA + kb + sksw],
             (char*)Blds + ch * 1024);
    }
    asm volatile("s_waitcnt vmcnt(0)" ::: "memory");
    __syncthreads();

#pragma unroll
    for (int c2 = 0; c2 < 2; ++c2) {
      bf16x8_t ar[4], br[2];
#pragma unroll
      for (int mi = 0; mi < 4; ++mi) {
        int row = wm * 64 + mi * 16 + lr;
        ar[mi] = *(const bf16x8_t*)&Alds[row * 64 + (((c2 * 4 + g) ^ (row & 7)) * 8)];
      }
#pragma unroll
      for (int ni = 0; ni < 2; ++ni) {
        int row = wn * 32 + ni * 16 + lr;
        br[ni] = *(const bf16x8_t*)&Blds[row * 64 + (((c2 * 4 + g) ^ (row & 7)) * 8)];
      }
#pragma unroll
      for (int mi = 0; mi < 4; ++mi)
#pragma unroll
        for (int ni = 0; ni < 2; ++ni)
          acc[mi][ni] = __builtin_amdgcn_mfma_f32_16x16x32_bf16(ar[mi], br[ni],
                                                                acc[mi][ni], 0, 0, 0);
    }
  }

#pragma unroll
  for (int ni = 0; ni < 2; ++ni) {
    int col = n0 + wn * 32 + ni * 16 + lr;
    float bv = bias[col];
#pragma unroll
    for (int mi = 0; mi < 4; ++mi) {
      int tokb = m0 + wm * 64 + mi * 16 + 4 * g;
#pragma unroll
      for (int r = 0; r < 4; ++r)
        out[(size_t)(tokb + r) * DM + col] = acc[mi][ni][r] + bv;
    }
  }
}

// ---------------------------------------------------------------------------
extern "C" void kernel_launch(void* const* d_in, const int* in_sizes, int n_in,
                              void* d_out, int out_size, void* d_ws, size_t ws_size,
                              hipStream_t stream) {
  const float* x = (const float*)d_in[0];
  const float* key_mask = (const float*)d_in[1];
  const float* W_qkv = (const float*)d_in[2];
  const float* b_qkv = (const float*)d_in[3];
  const float* W_out = (const float*)d_in[4];
  const float* b_out = (const float*)d_in[5];
  float* out = (float*)d_out;

  unsigned short* ws = (unsigned short*)d_ws;
  unsigned short* qbf = ws;                        // [BN][128] bf16 (pre-scaled)
  unsigned short* kpk = qbf + (size_t)BN * DA;     // packed K 32-tiles
  unsigned short* vpk = kpk + (size_t)BN * DA;     // packed V 32-tiles (sigma)
  unsigned short* ctx = vpk + (size_t)BN * DA;     // [BN][128] bf16
  unsigned short* xbf = ctx + (size_t)BN * DA;     // (unused region, kept for layout)
  unsigned short* WqT = xbf + (size_t)BN * DM;     // [384][512]
  unsigned short* WoT = WqT + (size_t)384 * 512;   // [512][128]
  // partials in their own region (ws is 256 MiB; ~60 MB used total)
  unsigned short* part_o = WoT + (size_t)512 * 128;         // [748][128][128] bf16
  float* part_ml = (float*)(part_o + (size_t)N_ITEMS * 16384);  // [748][128][2] f32

  prep_w_kernel<<<dim3(768), 256, 0, stream>>>(W_qkv, W_out, WqT, WoT);
  qkv_kernel<<<dim3(BN / 128, 3), 512, 0, stream>>>(x, WqT, b_qkv, qbf, kpk, vpk);
  attn_kernel<<<dim3(N_ITEMS), 256, 0, stream>>>(qbf, kpk, vpk, key_mask,
                                                 part_o, part_ml, ctx);
  combine_kernel<<<dim3(29 * 4, 4), 512, 0, stream>>>(part_o, part_ml, key_mask, ctx);
  outproj_kernel<<<dim3(BN / 128, 4), 512, 0, stream>>>(ctx, WoT, b_out, out);
}